// Round 1
// baseline (722.820 us; speedup 1.0000x reference)
//
#include <hip/hip_runtime.h>
#include <math.h>

namespace {
constexpr int kRows = 131072;
constexpr int kRowsPerBlock = 4;   // 4 waves of 64 per block
}

// In-register wave-wide 512-point complex DIF FFT.
// Entry: lane l, slot s holds x[s + 8*l]  (n1 = s in [0,8), n2 = l in [0,64)).
// Exit:  lane l, slot s holds X[f], f = bitrev6(l) + 64*bitrev3(s).
// Ordering is scrambled but CONSISTENT across calls — the consumer only does
// an order-invariant sum over all f, so no bit-reversal pass is needed.
__device__ __forceinline__ void fft512_wave(float re[8], float im[8], int lane) {
    // ---- cross-lane 64-point DIF FFT over lane index (same butterfly for all 8 slots)
    #pragma unroll
    for (int hs = 32; hs >= 1; hs >>= 1) {
        const int j = lane & (hs - 1);
        float sn, cs;
        __sincosf(-(float)M_PI * (float)j / (float)hs, &sn, &cs);
        const bool hi = (lane & hs) != 0;
        #pragma unroll
        for (int s = 0; s < 8; ++s) {
            const float vr = __shfl_xor(re[s], hs);
            const float vi = __shfl_xor(im[s], hs);
            const float sr = re[s] + vr;         // lo lane: a + b
            const float si = im[s] + vi;
            const float dr = vr - re[s];         // hi lane: partner=a, self=b -> a-b
            const float di = vi - im[s];
            const float tr = dr * cs - di * sn;  // (a-b) * W_{2hs}^j
            const float ti = dr * sn + di * cs;
            re[s] = hi ? tr : sr;
            im[s] = hi ? ti : si;
        }
    }
    // ---- mid twiddle: k2 = bitrev6(lane); slot s *= W_512^{s*k2}
    const int k2 = (int)(__brev((unsigned)lane) >> 26);
    float wr, wi;
    __sincosf(-2.0f * (float)M_PI * (float)k2 * (1.0f / 512.0f), &wi, &wr);
    float cr = wr, ci = wi;                      // w^1 for slot 1
    #pragma unroll
    for (int s = 1; s < 8; ++s) {
        const float xr = re[s], xi = im[s];
        re[s] = xr * cr - xi * ci;
        im[s] = xr * ci + xi * cr;
        if (s < 7) {
            const float nr = cr * wr - ci * wi;
            ci = cr * wi + ci * wr;
            cr = nr;
        }
    }
    // ---- per-lane 8-point DIF FFT over slots
    const float C = 0.70710678118654752f;
    // stage hs=4: pairs (s, s+4), twiddle W_8^s
    #pragma unroll
    for (int s = 0; s < 4; ++s) {
        const float ar = re[s], ai = im[s];
        const float br = re[s + 4], bi = im[s + 4];
        re[s] = ar + br; im[s] = ai + bi;
        const float dr = ar - br, di = ai - bi;
        float or_, oi_;
        if (s == 0)      { or_ = dr;             oi_ = di; }
        else if (s == 1) { or_ = C * (dr + di);  oi_ = C * (di - dr); }   // * (C - iC)
        else if (s == 2) { or_ = di;             oi_ = -dr; }             // * (-i)
        else             { or_ = C * (di - dr);  oi_ = -C * (dr + di); }  // * (-C - iC)
        re[s + 4] = or_; im[s + 4] = oi_;
    }
    // stage hs=2: blocks {0..3},{4..7}; twiddle W_4^j, j = s&1
    #pragma unroll
    for (int b = 0; b < 8; b += 4) {
        #pragma unroll
        for (int j = 0; j < 2; ++j) {
            const int i0 = b + j, i1 = b + j + 2;
            const float ar = re[i0], ai = im[i0];
            const float br = re[i1], bi = im[i1];
            re[i0] = ar + br; im[i0] = ai + bi;
            const float dr = ar - br, di = ai - bi;
            if (j == 0) { re[i1] = dr; im[i1] = di; }
            else        { re[i1] = di; im[i1] = -dr; }   // * (-i)
        }
    }
    // stage hs=1: adjacent pairs, twiddle 1
    #pragma unroll
    for (int i = 0; i < 8; i += 2) {
        const float ar = re[i], ai = im[i];
        const float br = re[i + 1], bi = im[i + 1];
        re[i] = ar + br;     im[i] = ai + bi;
        re[i + 1] = ar - br; im[i + 1] = ai - bi;
    }
}

// out[b] = Im( sum_f Z_f^2 * conj(T_f) ) / (2*D),  Z = FFT(h + i r), T = FFT(t)
__global__ __launch_bounds__(256) void HolE_fft_kernel(
        const float* __restrict__ h, const float* __restrict__ r,
        const float* __restrict__ t, float* __restrict__ out) {
    const int lane = (int)(threadIdx.x & 63);
    const int row = blockIdx.x * kRowsPerBlock + (int)(threadIdx.x >> 6);

    const float4* __restrict__ h4 = (const float4*)h;
    const float4* __restrict__ r4 = (const float4*)r;
    const float4* __restrict__ t4 = (const float4*)t;
    const long base4 = (long)row * 128 + (long)(lane * 2);

    float zr[8], zi[8], tre[8], tim[8];
    {
        const float4 a0 = h4[base4], a1 = h4[base4 + 1];
        const float4 b0 = r4[base4], b1 = r4[base4 + 1];
        const float4 c0 = t4[base4], c1 = t4[base4 + 1];
        zr[0] = a0.x; zr[1] = a0.y; zr[2] = a0.z; zr[3] = a0.w;
        zr[4] = a1.x; zr[5] = a1.y; zr[6] = a1.z; zr[7] = a1.w;
        zi[0] = b0.x; zi[1] = b0.y; zi[2] = b0.z; zi[3] = b0.w;
        zi[4] = b1.x; zi[5] = b1.y; zi[6] = b1.z; zi[7] = b1.w;
        tre[0] = c0.x; tre[1] = c0.y; tre[2] = c0.z; tre[3] = c0.w;
        tre[4] = c1.x; tre[5] = c1.y; tre[6] = c1.z; tre[7] = c1.w;
        #pragma unroll
        for (int s = 0; s < 8; ++s) tim[s] = 0.0f;
    }

    fft512_wave(zr, zi, lane);
    fft512_wave(tre, tim, lane);

    float acc = 0.0f;
    #pragma unroll
    for (int s = 0; s < 8; ++s) {
        // Im( (zr+i zi)^2 * (tr - i ti) ) = 2*zr*zi*tr - (zr^2 - zi^2)*ti
        acc += 2.0f * zr[s] * zi[s] * tre[s] - (zr[s] * zr[s] - zi[s] * zi[s]) * tim[s];
    }
    #pragma unroll
    for (int m = 32; m >= 1; m >>= 1) acc += __shfl_xor(acc, m);

    if (lane == 0) out[row] = acc * (1.0f / 1024.0f);   // 1/(2*D)
}

extern "C" void kernel_launch(void* const* d_in, const int* in_sizes, int n_in,
                              void* d_out, int out_size, void* d_ws, size_t ws_size,
                              hipStream_t stream) {
    const float* h = (const float*)d_in[0];
    const float* r = (const float*)d_in[1];
    const float* t = (const float*)d_in[2];
    float* out = (float*)d_out;
    const int blocks = kRows / kRowsPerBlock;   // 131072 / 4 = 32768
    HolE_fft_kernel<<<blocks, 256, 0, stream>>>(h, r, t, out);
}